// Round 4
// 367.899 us; speedup vs baseline: 1.3366x; 1.3366x over previous
//
#include <hip/hip_runtime.h>
#include <hip/hip_bf16.h>

#define B_ 4096
#define T_ 128
#define F_ 64
#define H_ 32
#define G_ 128  // 4*H

using short8 = __attribute__((ext_vector_type(8))) short;
using f32x4  = __attribute__((ext_vector_type(4))) float;

#define MFMA16(Af, Bf, Cf) __builtin_amdgcn_mfma_f32_16x16x32_bf16((Af), (Bf), (Cf), 0, 0, 0)

__device__ __forceinline__ float sigmoid_f(float z) {
    return __builtin_amdgcn_rcpf(1.0f + __expf(-z));
}
// float -> bf16 bits (RNE via hardware cvt)
__device__ __forceinline__ unsigned short bfb(float f) {
    return __builtin_bit_cast(unsigned short, __float2bfloat16(f));
}

// One wave (64 lanes) per 16-row batch tile. MFMA 16x16x32 bf16.
//   lane = 16*g + c   (g = lane>>4 in 0..3, c = lane&15)
// A-frag (x or h):  A[row=c][k = 8*g + i], i=0..7   (k-map identical on A and B sides,
// B-frag (weights): B[k = 8*g + i][col=c]            so any HW k-permutation cancels)
// C/D: D[row = 4*g + r][col = c]  (guide-verified layout)
// Gate tiles n=0..7 cover gate columns 16n..16n+15: i=(0,1) f=(2,3) g=(4,5) o=(6,7).
extern "C" __global__ __launch_bounds__(64, 1)
void lstm_ae(const float* __restrict__ x,
             const float* __restrict__ We,
             const float* __restrict__ Ue,
             const float* __restrict__ be,
             const float* __restrict__ Wd,
             const float* __restrict__ Ud,
             const float* __restrict__ bd,
             const float* __restrict__ Wout,
             const float* __restrict__ bout,
             float* __restrict__ out)
{
    const int lane = threadIdx.x;
    const int g = lane >> 4;
    const int c = lane & 15;
    const int b0 = blockIdx.x << 4;

    // h repack buffer: [16 rows][stride 40 bf16] (pad 32->40 keeps b128 reads 16B-aligned
    // and spreads banks). Single wave per block: no barriers needed, DS ops are in-order.
    __shared__ __align__(16) unsigned short hlds[16 * 40];

    // ---------------- encoder weights as register-stationary B-fragments ----------------
    short8 weF[8][2];   // We: K=64 -> 2 chunks of 32
    short8 ueF[8];      // Ue: K=32
#pragma unroll
    for (int n = 0; n < 8; ++n) {
#pragma unroll
        for (int kc = 0; kc < 2; ++kc)
#pragma unroll
            for (int i = 0; i < 8; ++i)
                weF[n][kc][i] = (short)bfb(We[(kc * 32 + 8 * g + i) * G_ + 16 * n + c]);
#pragma unroll
        for (int i = 0; i < 8; ++i)
            ueF[n][i] = (short)bfb(Ue[(8 * g + i) * G_ + 16 * n + c]);
    }
    f32x4 beC[8];  // bias splat as MFMA C-operand (z starts at bias, no per-step movs)
#pragma unroll
    for (int n = 0; n < 8; ++n) {
        float v = be[16 * n + c];
        f32x4 t; t[0] = v; t[1] = v; t[2] = v; t[3] = v;
        beC[n] = t;
    }

    const float* xr = x + (size_t)(b0 + c) * (T_ * F_);
    const int xo = 8 * g;

    // state: hfrag = A-fragment of h (bf16), cs = fp32 cell state
    short8 hfrag = (short8)0;  // h0 = 0
    float cs[2][4];
#pragma unroll
    for (int jh = 0; jh < 2; ++jh)
#pragma unroll
        for (int r = 0; r < 4; ++r) cs[jh][r] = 0.f;

    // prefetch x_0 (8 floats per K-chunk per lane, contiguous)
    f32x4 xa = *(const f32x4*)(xr + xo);
    f32x4 xb = *(const f32x4*)(xr + xo + 4);
    f32x4 xc = *(const f32x4*)(xr + 32 + xo);
    f32x4 xd = *(const f32x4*)(xr + 36 + xo);

    // =============================== encoder scan ===============================
#pragma unroll 1
    for (int t = 0; t < T_; ++t) {
        short8 xf0, xf1;
#pragma unroll
        for (int i = 0; i < 4; ++i) {
            xf0[i]     = (short)bfb(xa[i]);
            xf0[4 + i] = (short)bfb(xb[i]);
            xf1[i]     = (short)bfb(xc[i]);
            xf1[4 + i] = (short)bfb(xd[i]);
        }
        if (t + 1 < T_) {  // prefetch next x row (hidden behind this step's compute)
            const float* xn = xr + (t + 1) * F_;
            xa = *(const f32x4*)(xn + xo);
            xb = *(const f32x4*)(xn + xo + 4);
            xc = *(const f32x4*)(xn + 32 + xo);
            xd = *(const f32x4*)(xn + 36 + xo);
        }

        f32x4 acc[8];
#pragma unroll
        for (int n = 0; n < 8; ++n) {
            acc[n] = MFMA16(xf0, weF[n][0], beC[n]);
            acc[n] = MFMA16(xf1, weF[n][1], acc[n]);
            acc[n] = MFMA16(hfrag, ueF[n], acc[n]);
        }

        // gates: lane holds z for (batch row 4g+r, hidden j = c + 16*jh)
#pragma unroll
        for (int jh = 0; jh < 2; ++jh)
#pragma unroll
            for (int r = 0; r < 4; ++r) {
                float iv = sigmoid_f(acc[0 + jh][r]);
                float fv = sigmoid_f(acc[2 + jh][r]);
                float gv = fmaxf(acc[4 + jh][r], 0.f);
                float ov = sigmoid_f(acc[6 + jh][r]);
                float cc = fmaf(fv, cs[jh][r], iv * gv);
                cs[jh][r] = cc;
                float hv = ov * fmaxf(cc, 0.f);
                hlds[(4 * g + r) * 40 + c + 16 * jh] = bfb(hv);
            }
        // repack: A-frag of h_t (8 contiguous bf16 per lane, 16B-aligned b128 read)
        hfrag = *(const short8*)&hlds[c * 40 + 8 * g];
    }

    // ================= decoder constant input zd = bd + hT@Wd (once) =================
    short8 udF[8], woF[4];
    f32x4 zd[8], boC[4];
    {
        short8 wdF[8];
#pragma unroll
        for (int n = 0; n < 8; ++n)
#pragma unroll
            for (int i = 0; i < 8; ++i) {
                wdF[n][i] = (short)bfb(Wd[(8 * g + i) * G_ + 16 * n + c]);
                udF[n][i] = (short)bfb(Ud[(8 * g + i) * G_ + 16 * n + c]);
            }
#pragma unroll
        for (int m = 0; m < 4; ++m) {
#pragma unroll
            for (int i = 0; i < 8; ++i)
                woF[m][i] = (short)bfb(Wout[(8 * g + i) * F_ + 16 * m + c]);
            float v = bout[16 * m + c];
            f32x4 tb; tb[0] = v; tb[1] = v; tb[2] = v; tb[3] = v;
            boC[m] = tb;
        }
#pragma unroll
        for (int n = 0; n < 8; ++n) {
            float v = bd[16 * n + c];
            f32x4 tb; tb[0] = v; tb[1] = v; tb[2] = v; tb[3] = v;
            zd[n] = MFMA16(hfrag, wdF[n], tb);   // hfrag == hT here
        }
    }

    // reset recurrent state for decoder
    hfrag = (short8)0;
#pragma unroll
    for (int jh = 0; jh < 2; ++jh)
#pragma unroll
        for (int r = 0; r < 4; ++r) cs[jh][r] = 0.f;

    float* ob[4];
#pragma unroll
    for (int r = 0; r < 4; ++r)
        ob[r] = out + (size_t)(b0 + 4 * g + r) * (T_ * F_) + c;

    // ==================== decoder scan + fused output projection ====================
#pragma unroll 1
    for (int t = 0; t < T_; ++t) {
        f32x4 acc[8];
#pragma unroll
        for (int n = 0; n < 8; ++n)
            acc[n] = MFMA16(hfrag, udF[n], zd[n]);  // z = zd + h@Ud, bias pre-folded

#pragma unroll
        for (int jh = 0; jh < 2; ++jh)
#pragma unroll
            for (int r = 0; r < 4; ++r) {
                float iv = sigmoid_f(acc[0 + jh][r]);
                float fv = sigmoid_f(acc[2 + jh][r]);
                float gv = fmaxf(acc[4 + jh][r], 0.f);
                float ov = sigmoid_f(acc[6 + jh][r]);
                float cc = fmaf(fv, cs[jh][r], iv * gv);
                cs[jh][r] = cc;
                float hv = ov * fmaxf(cc, 0.f);
                hlds[(4 * g + r) * 40 + c + 16 * jh] = bfb(hv);
            }
        hfrag = *(const short8*)&hlds[c * 40 + 8 * g];

        // out[b, t, :] = bout + h_t @ Wout  (N=64 -> 4 tiles), D rows = batch, cols = feature
        f32x4 oac[4];
#pragma unroll
        for (int m = 0; m < 4; ++m)
            oac[m] = MFMA16(hfrag, woF[m], boC[m]);
#pragma unroll
        for (int m = 0; m < 4; ++m)
#pragma unroll
            for (int r = 0; r < 4; ++r)
                ob[r][t * F_ + 16 * m] = oac[m][r];
    }
}

extern "C" void kernel_launch(void* const* d_in, const int* in_sizes, int n_in,
                              void* d_out, int out_size, void* d_ws, size_t ws_size,
                              hipStream_t stream) {
    (void)in_sizes; (void)n_in; (void)d_ws; (void)ws_size; (void)out_size;
    const float* x    = (const float*)d_in[0];
    const float* We   = (const float*)d_in[1];
    const float* Ue   = (const float*)d_in[2];
    const float* be   = (const float*)d_in[3];
    const float* Wd   = (const float*)d_in[4];
    const float* Ud   = (const float*)d_in[5];
    const float* bd   = (const float*)d_in[6];
    const float* Wout = (const float*)d_in[7];
    const float* bout = (const float*)d_in[8];
    float* out = (float*)d_out;

    dim3 grid(B_ / 16), block(64);
    hipLaunchKernelGGL(lstm_ae, grid, block, 0, stream,
                       x, We, Ue, be, Wd, Ud, bd, Wout, bout, out);
}